// Round 2
// baseline (587.745 us; speedup 1.0000x reference)
//
#include <hip/hip_runtime.h>
#include <math.h>

#define NROWS 200000
#define C 384
#define G 383
#define M 384          // G + 1
#define EPS 1e-5f
#define SQRTC 19.595917942265423f   // sqrt(384)

#define NCHUNK (NROWS * (C / 4))    // 19,200,000 float4 chunks
#define NBLK1 1024
#define THR1 256
#define NBLK4 576                   // triple-sum blocks (M*M/256)

// ---------------- workspace layout (floats) ----------------
#define WS_PART  0                              // NBLK1 * 1152  [block][cnt|sum|ss][384]
#define WS_S2    (WS_PART + NBLK1 * 1152)       // 8 * 1152 stage-2 partials
#define WS_RED   (WS_S2 + 8 * 1152)             // (unused spare)
#define WS_PROTO (WS_RED + 1152)                // 384
#define WS_STD   (WS_PROTO + 384)               // 384
#define WS_P3    (WS_STD + 384)                 // NBLK4 triple-sum partials

// K1: flat float4 stream; per-block LDS accumulation; plain-store flush.
__global__ __launch_bounds__(THR1) void stats_kernel(const float4* __restrict__ pred4,
                                                     const int* __restrict__ tgt,
                                                     float* __restrict__ ws) {
    __shared__ float lc[384], ls[384], lq[384];
    const int tid = threadIdx.x;
    for (int i = tid; i < 384; i += THR1) { lc[i] = 0.f; ls[i] = 0.f; lq[i] = 0.f; }
    __syncthreads();

    const int gtid   = blockIdx.x * THR1 + tid;
    const int stride = NBLK1 * THR1;

    // group-size histogram (one pass over the 200k ids)
    for (int r = gtid; r < NROWS; r += stride)
        atomicAdd(&lc[tgt[r]], 1.0f);

    // main stream: each float4 chunk lies entirely in one row
    for (int q = gtid; q < NCHUNK; q += stride) {
        float4 v = pred4[q];
        int row  = q / 96;              // 96 chunks per row; compiler emits magic-mul
        int seg  = tgt[row];
        float s  = (v.x + v.y) + (v.z + v.w);
        float qq = fmaf(v.x, v.x, fmaf(v.y, v.y, fmaf(v.z, v.z, v.w * v.w)));
        atomicAdd(&ls[seg], s);         // ds_add_f32, fire-and-forget
        atomicAdd(&lq[seg], qq);
    }
    __syncthreads();

    float* dst = ws + (size_t)blockIdx.x * 1152;
    for (int i = tid; i < 384; i += THR1) {
        dst[i]       = lc[i];
        dst[384 + i] = ls[i];
        dst[768 + i] = lq[i];
    }
}

// K2: reduce NBLK1 partial vectors -> 8 stage-2 vectors (8-way split, no atomics).
// 9216 threads: j = column [0,1152), sub = which 1/8 of the blocks.
__global__ void reduce_kernel(float* __restrict__ ws) {
    const int t   = blockIdx.x * blockDim.x + threadIdx.x;   // [0, 9216)
    const int j   = t % 1152;
    const int sub = t / 1152;                                 // [0, 8)
    float acc = 0.f;
#pragma unroll 8
    for (int b = sub; b < NBLK1; b += 8)
        acc += ws[WS_PART + (size_t)b * 1152 + j];
    ws[WS_S2 + sub * 1152 + j] = acc;
}

// K3: combine the 8 stage-2 vectors and finalize mean/std per group.
__global__ void finalize_kernel(float* __restrict__ ws) {
    const int g = threadIdx.x;          // blockDim.x == 384
    float cnt_r = 0.f, sum = 0.f, ss = 0.f;
#pragma unroll
    for (int sub = 0; sub < 8; ++sub) {
        const float* s2 = ws + WS_S2 + sub * 1152;
        cnt_r += s2[g];
        sum   += s2[384 + g];
        ss    += s2[768 + g];
    }
    float mean = 0.f, sd = 0.f;
    if (g < G && cnt_r > 0.5f) {
        float cnt = cnt_r * (float)C;
        mean = sum / cnt;
        if (cnt_r > 1.5f) {
            float cs    = ss - cnt * mean * mean;
            float denom = fmaxf(cnt - 1.0f, 1.0f);
            sd = sqrtf(fmaxf(cs / denom, 0.f));
        }
    }
    ws[WS_PROTO + g] = mean;
    ws[WS_STD + g]   = sd;
}

// K4: one thread per (x,a); sum over b>a of s/(norm_ab + s + EPS); per-block partial.
__global__ void triple_sum_kernel(const float* __restrict__ ws,
                                  float* __restrict__ part3) {
    __shared__ float sp[M];
    __shared__ float sst[M];
    __shared__ float wsum[4];
    const int tid = threadIdx.x;

    for (int i = tid; i < M; i += blockDim.x) {
        sp[i]  = ws[WS_PROTO + i];
        sst[i] = ws[WS_STD + i];
    }
    __syncthreads();

    const int idx = blockIdx.x * blockDim.x + tid;   // idx = x*M + a
    float partial = 0.f;
    {
        const int x = idx / M;
        const int a = idx - x * M;
        const float pa = sp[a];
        const float u  = fabsf(pa - sp[x]);
        const float t  = u / (u * SQRTC + EPS);      // |d[x,a]|
        if (t > 0.f) {
            const float sa = sst[a];
            for (int b = a + 1; b < M; ++b) {
                float nab = fabsf(sp[b] - pa) * SQRTC;
                float s   = t * (sa + sst[b]);
                partial += s * __builtin_amdgcn_rcpf(nab + s + EPS);
            }
        }
    }

#pragma unroll
    for (int off = 32; off > 0; off >>= 1)
        partial += __shfl_down(partial, off);
    if ((tid & 63) == 0) wsum[tid >> 6] = partial;
    __syncthreads();
    if (tid == 0)
        part3[blockIdx.x] = wsum[0] + wsum[1] + wsum[2] + wsum[3];
}

// K5: reduce 576 block partials, scale, write scalar out.
__global__ void write_out_kernel(const float* __restrict__ part3,
                                 float* __restrict__ out) {
    __shared__ float wsum[9];
    const int tid = threadIdx.x;        // blockDim.x == 576
    float v = part3[tid];
#pragma unroll
    for (int off = 32; off > 0; off >>= 1)
        v += __shfl_down(v, off);
    if ((tid & 63) == 0) wsum[tid >> 6] = v;
    __syncthreads();
    if (tid == 0) {
        float acc = 0.f;
#pragma unroll
        for (int w = 0; w < 9; ++w) acc += wsum[w];
        out[0] = acc / ((float)M * (float)M * (float)M);
    }
}

extern "C" void kernel_launch(void* const* d_in, const int* in_sizes, int n_in,
                              void* d_out, int out_size, void* d_ws, size_t ws_size,
                              hipStream_t stream) {
    const float4* pred4 = (const float4*)d_in[0];
    const int*    tgt   = (const int*)d_in[1];
    float* ws  = (float*)d_ws;
    float* out = (float*)d_out;

    stats_kernel<<<NBLK1, THR1, 0, stream>>>(pred4, tgt, ws);
    reduce_kernel<<<36, 256, 0, stream>>>(ws);
    finalize_kernel<<<1, 384, 0, stream>>>(ws);
    triple_sum_kernel<<<NBLK4, 256, 0, stream>>>(ws, ws + WS_P3);
    write_out_kernel<<<1, 576, 0, stream>>>(ws + WS_P3, out);
}

// Round 3
// 436.021 us; speedup vs baseline: 1.3480x; 1.3480x over previous
//
#include <hip/hip_runtime.h>
#include <math.h>

#define NROWS 200000
#define C 384
#define G 383
#define M 384          // G + 1
#define EPS 1e-5f
#define SQRTC 19.595917942265423f   // sqrt(384)

#define NBLK1 1024
#define THR1 512                    // 8 waves/block; 1024*8 = 8192 waves = 32/CU
#define NWAVES ((NBLK1 * THR1) / 64)
#define NBLK4 576                   // triple-sum blocks (M*M/256)

// ---------------- workspace layout (floats) ----------------
#define WS_PART  0                              // NBLK1 * 1152  [block][cnt|sum|ss][384]
#define WS_S2    (WS_PART + NBLK1 * 1152)       // 8 * 1152 stage-2 partials
#define WS_PROTO (WS_S2 + 8 * 1152)             // 384
#define WS_STD   (WS_PROTO + 384)               // 384
#define WS_P3    (WS_STD + 384)                 // NBLK4 triple-sum partials

// K1: one wave per row. float4 loads (16B/lane), register shuffle-reduce,
// 3 LDS atomics per ROW (lane 0 only), per-block plain-store flush.
__global__ __launch_bounds__(THR1) void stats_kernel(const float4* __restrict__ pred4,
                                                     const int* __restrict__ tgt,
                                                     float* __restrict__ ws,
                                                     int n_rows) {
    __shared__ float lc[384], ls[384], lq[384];
    const int tid = threadIdx.x;
    for (int i = tid; i < 384; i += THR1) { lc[i] = 0.f; ls[i] = 0.f; lq[i] = 0.f; }
    __syncthreads();

    const int lane = tid & 63;
    const int wv   = (blockIdx.x * THR1 + tid) >> 6;

    for (int row = wv; row < n_rows; row += NWAVES) {
        const float4* rp = pred4 + (size_t)row * 96;   // 96 float4 chunks per row
        const int seg = tgt[row];                      // same-address broadcast load
        float4 v0 = rp[lane];
        float s = (v0.x + v0.y) + (v0.z + v0.w);
        float q = fmaf(v0.x, v0.x, fmaf(v0.y, v0.y, fmaf(v0.z, v0.z, v0.w * v0.w)));
        if (lane < 32) {
            float4 v1 = rp[64 + lane];
            s += (v1.x + v1.y) + (v1.z + v1.w);
            q += fmaf(v1.x, v1.x, fmaf(v1.y, v1.y, fmaf(v1.z, v1.z, v1.w * v1.w)));
        }
#pragma unroll
        for (int off = 32; off > 0; off >>= 1) {
            s += __shfl_down(s, off);
            q += __shfl_down(q, off);
        }
        if (lane == 0) {
            atomicAdd(&lc[seg], 1.0f);
            atomicAdd(&ls[seg], s);
            atomicAdd(&lq[seg], q);
        }
    }
    __syncthreads();

    float* dst = ws + (size_t)blockIdx.x * 1152;
    for (int i = tid; i < 384; i += THR1) {
        dst[i]       = lc[i];
        dst[384 + i] = ls[i];
        dst[768 + i] = lq[i];
    }
}

// K2: reduce NBLK1 partial vectors -> 8 stage-2 vectors (no atomics).
__global__ void reduce_kernel(float* __restrict__ ws) {
    const int t   = blockIdx.x * blockDim.x + threadIdx.x;   // [0, 9216)
    const int j   = t % 1152;
    const int sub = t / 1152;                                 // [0, 8)
    float acc = 0.f;
#pragma unroll 8
    for (int b = sub; b < NBLK1; b += 8)
        acc += ws[WS_PART + (size_t)b * 1152 + j];
    ws[WS_S2 + sub * 1152 + j] = acc;
}

// K3: combine the 8 stage-2 vectors and finalize mean/std per group.
__global__ void finalize_kernel(float* __restrict__ ws) {
    const int g = threadIdx.x;          // blockDim.x == 384
    float cnt_r = 0.f, sum = 0.f, ss = 0.f;
#pragma unroll
    for (int sub = 0; sub < 8; ++sub) {
        const float* s2 = ws + WS_S2 + sub * 1152;
        cnt_r += s2[g];
        sum   += s2[384 + g];
        ss    += s2[768 + g];
    }
    float mean = 0.f, sd = 0.f;
    if (g < G && cnt_r > 0.5f) {
        float cnt = cnt_r * (float)C;
        mean = sum / cnt;
        if (cnt_r > 1.5f) {
            float cs    = ss - cnt * mean * mean;
            float denom = fmaxf(cnt - 1.0f, 1.0f);
            sd = sqrtf(fmaxf(cs / denom, 0.f));
        }
    }
    ws[WS_PROTO + g] = mean;
    ws[WS_STD + g]   = sd;
}

// K4: one thread per (x,a); sum over b>a of s/(norm_ab + s + EPS); per-block partial.
__global__ void triple_sum_kernel(const float* __restrict__ ws,
                                  float* __restrict__ part3) {
    __shared__ float sp[M];
    __shared__ float sst[M];
    __shared__ float wsum[4];
    const int tid = threadIdx.x;

    for (int i = tid; i < M; i += blockDim.x) {
        sp[i]  = ws[WS_PROTO + i];
        sst[i] = ws[WS_STD + i];
    }
    __syncthreads();

    const int idx = blockIdx.x * blockDim.x + tid;   // idx = x*M + a
    float partial = 0.f;
    {
        const int x = idx / M;
        const int a = idx - x * M;
        const float pa = sp[a];
        const float u  = fabsf(pa - sp[x]);
        const float t  = u / (u * SQRTC + EPS);      // |d[x,a]|
        if (t > 0.f) {
            const float sa = sst[a];
#pragma unroll 4
            for (int b = a + 1; b < M; ++b) {
                float nab = fabsf(sp[b] - pa) * SQRTC;
                float s   = t * (sa + sst[b]);
                partial += s * __builtin_amdgcn_rcpf(nab + s + EPS);
            }
        }
    }

#pragma unroll
    for (int off = 32; off > 0; off >>= 1)
        partial += __shfl_down(partial, off);
    if ((tid & 63) == 0) wsum[tid >> 6] = partial;
    __syncthreads();
    if (tid == 0)
        part3[blockIdx.x] = wsum[0] + wsum[1] + wsum[2] + wsum[3];
}

// K5: reduce 576 block partials, scale, write scalar out.
__global__ void write_out_kernel(const float* __restrict__ part3,
                                 float* __restrict__ out) {
    __shared__ float wsum[9];
    const int tid = threadIdx.x;        // blockDim.x == 576
    float v = part3[tid];
#pragma unroll
    for (int off = 32; off > 0; off >>= 1)
        v += __shfl_down(v, off);
    if ((tid & 63) == 0) wsum[tid >> 6] = v;
    __syncthreads();
    if (tid == 0) {
        float acc = 0.f;
#pragma unroll
        for (int w = 0; w < 9; ++w) acc += wsum[w];
        out[0] = acc / ((float)M * (float)M * (float)M);
    }
}

extern "C" void kernel_launch(void* const* d_in, const int* in_sizes, int n_in,
                              void* d_out, int out_size, void* d_ws, size_t ws_size,
                              hipStream_t stream) {
    const float4* pred4 = (const float4*)d_in[0];
    const int*    tgt   = (const int*)d_in[1];
    float* ws  = (float*)d_ws;
    float* out = (float*)d_out;
    const int n_rows = in_sizes[1];

    stats_kernel<<<NBLK1, THR1, 0, stream>>>(pred4, tgt, ws, n_rows);
    reduce_kernel<<<36, 256, 0, stream>>>(ws);
    finalize_kernel<<<1, 384, 0, stream>>>(ws);
    triple_sum_kernel<<<NBLK4, 256, 0, stream>>>(ws, ws + WS_P3);
    write_out_kernel<<<1, 576, 0, stream>>>(ws + WS_P3, out);
}